// Round 14
// baseline (65.793 us; speedup 1.0000x reference)
//
#include <hip/hip_runtime.h>
#include <math.h>
#include <utility>
#include <type_traits>

namespace {

constexpr int C_  = 16;
constexpr int OR_ = 8;
constexpr int H_  = 192;
constexpr int W_  = 192;
constexpr int HW_ = H_ * W_;
constexpr int CH_ = OR_ * HW_;
constexpr float PI_F = 3.14159265358979323846f;

// Padded fp16 conv-output workspace: image px (y,x) -> padded (y+2, x+2).
constexpr int PH_  = 196;
constexpr int PW_  = 208;             // row = 416 B (16B multiple)
constexpr int PPL_ = PH_ * PW_;       // 40768 halves per plane
constexpr int NPL_ = C_ * OR_;        // 128 planes
constexpr int PAD_CELLS = 2 * PW_ + 2 * PW_ + H_ * 16;   // 3904 border cells/plane
constexpr int PAD_PER_BLOCK = 109;    // 36 blocks/plane * 109 >= 3904

typedef _Float16 h4 __attribute__((ext_vector_type(4)));
typedef float f2u __attribute__((ext_vector_type(2), aligned(4)));   // dword-aligned 8B load
typedef _Float16 h2u __attribute__((ext_vector_type(2), aligned(2)));

constexpr float SQ2H = 0.70710678118654752440f;
constexpr float CT8[8] = { 1.0f,  SQ2H,  0.0f, -SQ2H, -1.0f, -SQ2H,  0.0f,  SQ2H };
constexpr float ST8[8] = { 0.0f,  SQ2H,  1.0f,  SQ2H,  0.0f, -SQ2H, -1.0f, -SQ2H };

constexpr int cfloor(float v) {
    return (v >= 0.0f) ? (int)v : (((float)(int)v == v) ? (int)v : (int)v - 1);
}

// Zero-padded corner fetch (matches reference _sample's per-corner validity).
template<typename SrcT>
__device__ __forceinline__ float cornerT(const SrcT* __restrict__ p, int iy, int ix) {
    bool valid = ((unsigned)iy < (unsigned)H_) && ((unsigned)ix < (unsigned)W_);
    int yc = min(max(iy, 0), H_ - 1);
    int xc = min(max(ix, 0), W_ - 1);
    float v = (float)p[yc * W_ + xc];
    return valid ? v : 0.0f;
}

// 8B pair load (f32 or fp16 source), returns {col0, col1} as floats.
template<typename SrcT>
__device__ __forceinline__ f2u pair2(const SrcT* __restrict__ p, int o) {
    if constexpr (std::is_same_v<SrcT, float>) {
        return *(const f2u*)(p + o);
    } else {
        const h2u h = *(const h2u*)(p + o);
        f2u r; r[0] = (float)h[0]; r[1] = (float)h[1];
        return r;
    }
}

// ---------------- convection_m2 (round-11 structure, paired loads) ------------
template<typename SrcT>
__global__ __launch_bounds__(256) void conv_kernel(
        const SrcT* __restrict__ u, const float* __restrict__ g0,
        _Float16* __restrict__ wsA) {
    const int t = threadIdx.x;
    const int tx  = t & 63;
    const int ty0 = (t >> 6) * 4;
    const int x   = blockIdx.x * 64 + tx;
    const int y0  = blockIdx.y * 16 + ty0;
    const int z = blockIdx.z;
    const int c  = z >> 3;
    const int th = z & 7;

    // ---- pad-border zeroing (36 blocks/plane x 109 cells) ----
    {
        const int bi = blockIdx.y * 3 + blockIdx.x;          // 0..35
        const int idx = bi * PAD_PER_BLOCK + t;
        if (t < PAD_PER_BLOCK && idx < PAD_CELLS) {
            int i = idx, r, col;
            if (i < 2 * PW_)      { r = i / PW_;            col = i % PW_; }
            else if (i < 4 * PW_) { i -= 2 * PW_; r = 194 + i / PW_; col = i % PW_; }
            else { i -= 4 * PW_; r = 2 + (i >> 4); const int cs = i & 15;
                   col = (cs < 2) ? cs : (192 + cs); }
            wsA[z * PPL_ + r * PW_ + col] = (_Float16)0.0f;
        }
    }

    const float gx0  = g0[c * 3 + 0];
    const float gy0  = g0[c * 3 + 1];
    const float gth0 = g0[c * 3 + 2];

    float sa, ca;
    sincosf((float)th * (2.0f * PI_F / OR_) - gth0, &sa, &ca);
    const float dxs = ca * gx0 - sa * gy0;
    const float dys = sa * gx0 + ca * gy0;

    const float fx = (float)x - dxs;
    const float fy = (float)y0 - dys;
    const float fx0 = floorf(fx), fy0 = floorf(fy);
    const float wx = fx - fx0, wy = fy - fy0;
    const int ix0 = (int)fx0, iy0 = (int)fy0;

    float tc = (float)th - gth0 * (OR_ / (2.0f * PI_F));
    tc = tc - floorf(tc * (1.0f / OR_)) * (float)OR_;
    const float t0f = floorf(tc);
    const float wt = tc - t0f;
    const int t0i = ((int)t0f) & 7;
    const int t1i = (t0i + 1) & 7;

    const SrcT* __restrict__ p0 = u + c * CH_ + t0i * HW_;
    const SrcT* __restrict__ p1 = u + c * CH_ + t1i * HW_;

    float r0, r1, r2, r3;
    if (ix0 >= 0 && ix0 + 1 < W_ && iy0 >= 0 && iy0 + 4 < H_) {
        const int o = iy0 * W_ + ix0;
        // 10 x 8B paired loads (5 rows x 2 planes)
        const f2u A0 = pair2(p0, o);
        const f2u A1 = pair2(p0, o + W_);
        const f2u A2 = pair2(p0, o + 2 * W_);
        const f2u A3 = pair2(p0, o + 3 * W_);
        const f2u A4 = pair2(p0, o + 4 * W_);
        const f2u B0 = pair2(p1, o);
        const f2u B1 = pair2(p1, o + W_);
        const f2u B2 = pair2(p1, o + 2 * W_);
        const f2u B3 = pair2(p1, o + 3 * W_);
        const f2u B4 = pair2(p1, o + 4 * W_);
        const float ha0 = A0[0] + wx * (A0[1] - A0[0]);
        const float ha1 = A1[0] + wx * (A1[1] - A1[0]);
        const float ha2 = A2[0] + wx * (A2[1] - A2[0]);
        const float ha3 = A3[0] + wx * (A3[1] - A3[0]);
        const float ha4 = A4[0] + wx * (A4[1] - A4[0]);
        const float hb0 = B0[0] + wx * (B0[1] - B0[0]);
        const float hb1 = B1[0] + wx * (B1[1] - B1[0]);
        const float hb2 = B2[0] + wx * (B2[1] - B2[0]);
        const float hb3 = B3[0] + wx * (B3[1] - B3[0]);
        const float hb4 = B4[0] + wx * (B4[1] - B4[0]);
        const float va0 = ha0 + wy * (ha1 - ha0);
        const float va1 = ha1 + wy * (ha2 - ha1);
        const float va2 = ha2 + wy * (ha3 - ha2);
        const float va3 = ha3 + wy * (ha4 - ha3);
        const float vb0 = hb0 + wy * (hb1 - hb0);
        const float vb1 = hb1 + wy * (hb2 - hb1);
        const float vb2 = hb2 + wy * (hb3 - hb2);
        const float vb3 = hb3 + wy * (hb4 - hb3);
        r0 = va0 + wt * (vb0 - va0);
        r1 = va1 + wt * (vb1 - va1);
        r2 = va2 + wt * (vb2 - va2);
        r3 = va3 + wt * (vb3 - va3);
    } else {
        const float w00 = (1.f - wy) * (1.f - wx);
        const float w01 = (1.f - wy) * wx;
        const float w10 = wy * (1.f - wx);
        const float w11 = wy * wx;
        float rr[4];
        #pragma unroll
        for (int j = 0; j < 4; ++j) {
            const int iy = iy0 + j;
            float v0 = w00 * cornerT(p0, iy, ix0)     + w01 * cornerT(p0, iy, ix0 + 1)
                     + w10 * cornerT(p0, iy + 1, ix0) + w11 * cornerT(p0, iy + 1, ix0 + 1);
            float v1 = w00 * cornerT(p1, iy, ix0)     + w01 * cornerT(p1, iy, ix0 + 1)
                     + w10 * cornerT(p1, iy + 1, ix0) + w11 * cornerT(p1, iy + 1, ix0 + 1);
            rr[j] = v0 + wt * (v1 - v0);
        }
        r0 = rr[0]; r1 = rr[1]; r2 = rr[2]; r3 = rr[3];
    }
    _Float16* __restrict__ op = wsA + z * PPL_ + (y0 + 2) * PW_ + (x + 2);
    op[0]       = (_Float16)r0;
    op[PW_]     = (_Float16)r1;
    op[2 * PW_] = (_Float16)r2;
    op[3 * PW_] = (_Float16)r3;
}

// ---------------- dilation: 4x2 px per thread, 6x8 windows (round-12 exact) ---
template<int TH, int PP, int OO>
__device__ __forceinline__ void off_one(const float (&w)[6][8],
        const float* __restrict__ sk, float (&ac0)[4], float (&ac1)[4]) {
    constexpr int hxi = OO % 3 - 1;
    constexpr int hyi = OO / 3 - 1;
    constexpr float ct = CT8[TH];
    constexpr float st = ST8[TH];
    constexpr float sx = ct * (float)hxi - st * (float)hyi;
    constexpr float sy = st * (float)hxi + ct * (float)hyi;
    constexpr int dx = cfloor(sx);
    constexpr int dy = cfloor(sy);
    constexpr float wx = sx - (float)dx;
    constexpr float wy = sy - (float)dy;
    constexpr int R  = dy + 2;    // 0..3
    constexpr int Cb = dx + 2;    // 0..3

    const float k = sk[PP * 9 + OO];   // wave-uniform LDS broadcast
    #pragma unroll
    for (int j = 0; j < 4; ++j) {
        float v0, v1;
        if constexpr (wx == 0.0f && wy == 0.0f) {
            v0 = w[R][Cb + j];
            v1 = w[R + 1][Cb + j];
        } else if constexpr (wy == 0.0f) {
            const float a = w[R][Cb + j],     a1 = w[R][Cb + j + 1];
            const float b = w[R + 1][Cb + j], b1 = w[R + 1][Cb + j + 1];
            v0 = a + wx * (a1 - a);
            v1 = b + wx * (b1 - b);
        } else if constexpr (wx == 0.0f) {
            const float a  = w[R][Cb + j];
            const float b  = w[R + 1][Cb + j];
            const float cc = w[R + 2][Cb + j];
            v0 = a + wy * (b - a);
            v1 = b + wy * (cc - b);
        } else {
            const float a  = w[R][Cb + j],     a1  = w[R][Cb + j + 1];
            const float b  = w[R + 1][Cb + j], b1  = w[R + 1][Cb + j + 1];
            const float cc = w[R + 2][Cb + j], cc1 = w[R + 2][Cb + j + 1];
            const float h0 = a  + wx * (a1 - a);
            const float h1 = b  + wx * (b1 - b);      // shared by both rows
            const float h2 = cc + wx * (cc1 - cc);
            v0 = h0 + wy * (h1 - h0);
            v1 = h1 + wy * (h2 - h1);
        }
        ac0[j] = fmaxf(ac0[j], v0 - k);
        ac1[j] = fmaxf(ac1[j], v1 - k);
    }
}

template<int TH, int PP, int... OOs>
__device__ __forceinline__ void off_nine(std::integer_sequence<int, OOs...>,
        const float (&w)[6][8], const float* __restrict__ sk,
        float (&ac0)[4], float (&ac1)[4]) {
    (off_one<TH, PP, OOs>(w, sk, ac0, ac1), ...);
}

// Plane slot PP (hti = PP-1): 12 x 8B fp16 loads -> f32 6x8 window.
template<int TH, int PP>
__device__ __forceinline__ void do_plane(const _Float16* __restrict__ wb,
        const float* __restrict__ sk, float (&ac0)[4], float (&ac1)[4]) {
    constexpr int plane = (TH + PP - 1 + OR_) & 7;
    float w[6][8];
    const _Float16* __restrict__ base = wb + plane * PPL_;
    #pragma unroll
    for (int r = 0; r < 6; ++r) {
        const h4 lo = *(const h4*)&base[r * PW_];
        const h4 hi = *(const h4*)&base[r * PW_ + 4];
        #pragma unroll
        for (int j = 0; j < 4; ++j) {
            w[r][j]     = (float)lo[j];
            w[r][4 + j] = (float)hi[j];
        }
    }
    off_nine<TH, PP>(std::make_integer_sequence<int, 9>{}, w, sk, ac0, ac1);
}

template<int TH>
__device__ __forceinline__ void dil_theta(const _Float16* __restrict__ wb,
        const float* __restrict__ sk, float (&ac0)[4], float (&ac1)[4]) {
    do_plane<TH, 0>(wb, sk, ac0, ac1);
    do_plane<TH, 1>(wb, sk, ac0, ac1);
    do_plane<TH, 2>(wb, sk, ac0, ac1);
}

// One block per (c,theta, 64x32 tile): windows straight from padded fp16 ws.
template<typename DstT>
__global__ __launch_bounds__(256) void dil_kernel(
        const _Float16* __restrict__ wsA, const float* __restrict__ mp,
        DstT* __restrict__ out) {
    __shared__ float s_k[27];

    const int z = blockIdx.z;
    const int c  = z >> 3;
    const int th = z & 7;
    const int t = threadIdx.x;

    if (t < 27) {
        const int hti = t / 9 - 1;
        const int hyi = (t / 3) % 3 - 1;
        const int hxi = t % 3 - 1;
        const float hx = (float)hxi, hy = (float)hyi;
        const float hth  = (float)hti * (2.0f * PI_F / OR_);
        const float half = 0.5f * hth;
        float q;
        if (fabsf(half) < 1e-4f) q = 1.0f - half * half * (1.0f / 3.0f);
        else                     q = half / tanf(half);
        const float c1 = q * hx + half * hy;
        const float c2 = -half * hx + q * hy;
        const float c3 = hth;
        const float m0 = mp[c * 3 + 0], m1 = mp[c * 3 + 1], m2 = mp[c * 3 + 2];
        const float d2 = (m0 * c1) * (m0 * c1) + (m1 * c2) * (m1 * c2) + (m2 * c3) * (m2 * c3);
        const float ee = 2.0f * 0.65f / (2.0f * 0.65f - 1.0f);
        const float nu = (2.0f * 0.65f - 1.0f) * powf(2.0f * 0.65f, -ee);
        s_k[t] = nu * powf(d2, 0.5f * ee);
    }
    __syncthreads();

    const int xg = t & 15;                       // 4 px: gx..gx+3
    const int ry = t >> 4;                       // 0..15, 2 rows each
    const int gx = blockIdx.x * 64 + xg * 4;
    const int gy = blockIdx.y * 32 + ry * 2;

    // window base: padded (gy, gx) == image (gy-2, gx-2)
    const _Float16* __restrict__ wb = wsA + c * OR_ * PPL_ + gy * PW_ + gx;

    float ac0[4], ac1[4];
    #pragma unroll
    for (int j = 0; j < 4; ++j) { ac0[j] = -INFINITY; ac1[j] = -INFINITY; }

    switch (th) {
        case 0: dil_theta<0>(wb, s_k, ac0, ac1); break;
        case 1: dil_theta<1>(wb, s_k, ac0, ac1); break;
        case 2: dil_theta<2>(wb, s_k, ac0, ac1); break;
        case 3: dil_theta<3>(wb, s_k, ac0, ac1); break;
        case 4: dil_theta<4>(wb, s_k, ac0, ac1); break;
        case 5: dil_theta<5>(wb, s_k, ac0, ac1); break;
        case 6: dil_theta<6>(wb, s_k, ac0, ac1); break;
        case 7: dil_theta<7>(wb, s_k, ac0, ac1); break;
        default: __builtin_unreachable();
    }

    const int o = c * CH_ + th * HW_ + gy * W_ + gx;
    if constexpr (std::is_same_v<DstT, float>) {
        float4 r0, r1;
        r0.x = ac0[0]; r0.y = ac0[1]; r0.z = ac0[2]; r0.w = ac0[3];
        r1.x = ac1[0]; r1.y = ac1[1]; r1.z = ac1[2]; r1.w = ac1[3];
        *(float4*)&out[o] = r0;
        *(float4*)&out[o + W_] = r1;
    } else {
        h4 r0, r1;
        r0[0] = (_Float16)ac0[0]; r0[1] = (_Float16)ac0[1];
        r0[2] = (_Float16)ac0[2]; r0[3] = (_Float16)ac0[3];
        r1[0] = (_Float16)ac1[0]; r1[1] = (_Float16)ac1[1];
        r1[2] = (_Float16)ac1[2]; r1[3] = (_Float16)ac1[3];
        *(h4*)&out[o] = r0;
        *(h4*)&out[o + W_] = r1;
    }
}

} // anonymous namespace

extern "C" void kernel_launch(void* const* d_in, const int* in_sizes, int n_in,
                              void* d_out, int out_size, void* d_ws, size_t ws_size,
                              hipStream_t stream) {
    const float* u   = (const float*)d_in[0];
    const float* g0  = (const float*)d_in[1];
    const float* mpp = (const float*)d_in[2];
    float* out = (float*)d_out;
    _Float16* wsA = (_Float16*)d_ws;                 // padded fp16 conv output, 10.4 MB
    _Float16* wsB = wsA + NPL_ * PPL_;               // fp16 dil-1 output, 9.4 MB

    dim3 cgrid(W_ / 64, H_ / 16, C_ * OR_);          // conv: 4608 blocks
    dim3 dgrid(W_ / 64, H_ / 32, C_ * OR_);          // dil:  2304 blocks
    dim3 block(256);

    // iter 1
    conv_kernel<float>   <<<cgrid, block, 0, stream>>>(u,   g0,  wsA);
    dil_kernel<_Float16> <<<dgrid, block, 0, stream>>>(wsA, mpp, wsB);
    // iter 2
    conv_kernel<_Float16><<<cgrid, block, 0, stream>>>(wsB, g0,  wsA);
    dil_kernel<float>    <<<dgrid, block, 0, stream>>>(wsA, mpp, out);
}

// Round 15
// 60.297 us; speedup vs baseline: 1.0911x; 1.0911x over previous
//
#include <hip/hip_runtime.h>
#include <math.h>
#include <utility>
#include <type_traits>

namespace {

constexpr int C_  = 16;
constexpr int OR_ = 8;
constexpr int H_  = 192;
constexpr int W_  = 192;
constexpr int HW_ = H_ * W_;
constexpr int CH_ = OR_ * HW_;
constexpr float PI_F = 3.14159265358979323846f;

// Padded fp16 conv-output workspace: image px (y,x) -> padded (y+2, x+2).
constexpr int PH_  = 196;
constexpr int PW_  = 208;             // row = 416 B (16B multiple)
constexpr int PPL_ = PH_ * PW_;       // 40768 halves per plane
constexpr int NPL_ = C_ * OR_;        // 128 planes
constexpr int PAD_CELLS = 2 * PW_ + 2 * PW_ + H_ * 16;   // 3904 border cells/plane
constexpr int PAD_PER_BLOCK = 109;    // 36 blocks/plane * 109 >= 3904

typedef _Float16 h4 __attribute__((ext_vector_type(4)));
typedef float f2u __attribute__((ext_vector_type(2), aligned(4)));   // dword-aligned 8B load
typedef _Float16 h2u __attribute__((ext_vector_type(2), aligned(2)));

constexpr float SQ2H = 0.70710678118654752440f;
constexpr float CT8[8] = { 1.0f,  SQ2H,  0.0f, -SQ2H, -1.0f, -SQ2H,  0.0f,  SQ2H };
constexpr float ST8[8] = { 0.0f,  SQ2H,  1.0f,  SQ2H,  0.0f, -SQ2H, -1.0f, -SQ2H };

constexpr int cfloor(float v) {
    return (v >= 0.0f) ? (int)v : (((float)(int)v == v) ? (int)v : (int)v - 1);
}

// Zero-padded corner fetch (matches reference _sample's per-corner validity).
template<typename SrcT>
__device__ __forceinline__ float cornerT(const SrcT* __restrict__ p, int iy, int ix) {
    bool valid = ((unsigned)iy < (unsigned)H_) && ((unsigned)ix < (unsigned)W_);
    int yc = min(max(iy, 0), H_ - 1);
    int xc = min(max(ix, 0), W_ - 1);
    float v = (float)p[yc * W_ + xc];
    return valid ? v : 0.0f;
}

// 8B pair load (f32 or fp16 source), returns {col0, col1} as floats.
template<typename SrcT>
__device__ __forceinline__ f2u pair2(const SrcT* __restrict__ p, int o) {
    if constexpr (std::is_same_v<SrcT, float>) {
        return *(const f2u*)(p + o);
    } else {
        const h2u h = *(const h2u*)(p + o);
        f2u r; r[0] = (float)h[0]; r[1] = (float)h[1];
        return r;
    }
}

// ---------------- convection_m2 (round-13 body, XCD-pinned 1-D grid) ----------
// block id = (n<<4)|c, n = th*36 + tile  ->  id%8 == c%8  (channel->XCD pin)
template<typename SrcT>
__global__ __launch_bounds__(256) void conv_kernel(
        const SrcT* __restrict__ u, const float* __restrict__ g0,
        _Float16* __restrict__ wsA) {
    const int id = blockIdx.x;
    const int c    = id & 15;
    const int n    = id >> 4;          // 0..287
    const int th   = n / 36;
    const int tile = n - th * 36;      // 0..35
    const int bx   = tile % 3;
    const int by   = tile / 3;         // 0..11
    const int z    = (c << 3) | th;

    const int t = threadIdx.x;
    const int tx  = t & 63;
    const int ty0 = (t >> 6) * 4;
    const int x   = bx * 64 + tx;
    const int y0  = by * 16 + ty0;

    // ---- pad-border zeroing (36 blocks/plane x 109 cells) ----
    {
        const int idx = tile * PAD_PER_BLOCK + t;
        if (t < PAD_PER_BLOCK && idx < PAD_CELLS) {
            int i = idx, r, col;
            if (i < 2 * PW_)      { r = i / PW_;            col = i % PW_; }
            else if (i < 4 * PW_) { i -= 2 * PW_; r = 194 + i / PW_; col = i % PW_; }
            else { i -= 4 * PW_; r = 2 + (i >> 4); const int cs = i & 15;
                   col = (cs < 2) ? cs : (192 + cs); }
            wsA[z * PPL_ + r * PW_ + col] = (_Float16)0.0f;
        }
    }

    const float gx0  = g0[c * 3 + 0];
    const float gy0  = g0[c * 3 + 1];
    const float gth0 = g0[c * 3 + 2];

    float sa, ca;
    sincosf((float)th * (2.0f * PI_F / OR_) - gth0, &sa, &ca);
    const float dxs = ca * gx0 - sa * gy0;
    const float dys = sa * gx0 + ca * gy0;

    const float fx = (float)x - dxs;
    const float fy = (float)y0 - dys;
    const float fx0 = floorf(fx), fy0 = floorf(fy);
    const float wx = fx - fx0, wy = fy - fy0;
    const int ix0 = (int)fx0, iy0 = (int)fy0;

    float tc = (float)th - gth0 * (OR_ / (2.0f * PI_F));
    tc = tc - floorf(tc * (1.0f / OR_)) * (float)OR_;
    const float t0f = floorf(tc);
    const float wt = tc - t0f;
    const int t0i = ((int)t0f) & 7;
    const int t1i = (t0i + 1) & 7;

    const SrcT* __restrict__ p0 = u + c * CH_ + t0i * HW_;
    const SrcT* __restrict__ p1 = u + c * CH_ + t1i * HW_;

    float r0, r1, r2, r3;
    if (ix0 >= 0 && ix0 + 1 < W_ && iy0 >= 0 && iy0 + 4 < H_) {
        const int o = iy0 * W_ + ix0;
        const f2u A0 = pair2(p0, o);
        const f2u A1 = pair2(p0, o + W_);
        const f2u A2 = pair2(p0, o + 2 * W_);
        const f2u A3 = pair2(p0, o + 3 * W_);
        const f2u A4 = pair2(p0, o + 4 * W_);
        const f2u B0 = pair2(p1, o);
        const f2u B1 = pair2(p1, o + W_);
        const f2u B2 = pair2(p1, o + 2 * W_);
        const f2u B3 = pair2(p1, o + 3 * W_);
        const f2u B4 = pair2(p1, o + 4 * W_);
        const float ha0 = A0[0] + wx * (A0[1] - A0[0]);
        const float ha1 = A1[0] + wx * (A1[1] - A1[0]);
        const float ha2 = A2[0] + wx * (A2[1] - A2[0]);
        const float ha3 = A3[0] + wx * (A3[1] - A3[0]);
        const float ha4 = A4[0] + wx * (A4[1] - A4[0]);
        const float hb0 = B0[0] + wx * (B0[1] - B0[0]);
        const float hb1 = B1[0] + wx * (B1[1] - B1[0]);
        const float hb2 = B2[0] + wx * (B2[1] - B2[0]);
        const float hb3 = B3[0] + wx * (B3[1] - B3[0]);
        const float hb4 = B4[0] + wx * (B4[1] - B4[0]);
        const float va0 = ha0 + wy * (ha1 - ha0);
        const float va1 = ha1 + wy * (ha2 - ha1);
        const float va2 = ha2 + wy * (ha3 - ha2);
        const float va3 = ha3 + wy * (ha4 - ha3);
        const float vb0 = hb0 + wy * (hb1 - hb0);
        const float vb1 = hb1 + wy * (hb2 - hb1);
        const float vb2 = hb2 + wy * (hb3 - hb2);
        const float vb3 = hb3 + wy * (hb4 - hb3);
        r0 = va0 + wt * (vb0 - va0);
        r1 = va1 + wt * (vb1 - va1);
        r2 = va2 + wt * (vb2 - va2);
        r3 = va3 + wt * (vb3 - va3);
    } else {
        const float w00 = (1.f - wy) * (1.f - wx);
        const float w01 = (1.f - wy) * wx;
        const float w10 = wy * (1.f - wx);
        const float w11 = wy * wx;
        float rr[4];
        #pragma unroll
        for (int j = 0; j < 4; ++j) {
            const int iy = iy0 + j;
            float v0 = w00 * cornerT(p0, iy, ix0)     + w01 * cornerT(p0, iy, ix0 + 1)
                     + w10 * cornerT(p0, iy + 1, ix0) + w11 * cornerT(p0, iy + 1, ix0 + 1);
            float v1 = w00 * cornerT(p1, iy, ix0)     + w01 * cornerT(p1, iy, ix0 + 1)
                     + w10 * cornerT(p1, iy + 1, ix0) + w11 * cornerT(p1, iy + 1, ix0 + 1);
            rr[j] = v0 + wt * (v1 - v0);
        }
        r0 = rr[0]; r1 = rr[1]; r2 = rr[2]; r3 = rr[3];
    }
    _Float16* __restrict__ op = wsA + z * PPL_ + (y0 + 2) * PW_ + (x + 2);
    op[0]       = (_Float16)r0;
    op[PW_]     = (_Float16)r1;
    op[2 * PW_] = (_Float16)r2;
    op[3 * PW_] = (_Float16)r3;
}

// ---------------- dilation (round-13 body, XCD-pinned 1-D grid) ---------------
template<int TH, int PP, int OO>
__device__ __forceinline__ void off_one(const float (&w)[6][8],
        const float* __restrict__ sk, float (&ac0)[4], float (&ac1)[4]) {
    constexpr int hxi = OO % 3 - 1;
    constexpr int hyi = OO / 3 - 1;
    constexpr float ct = CT8[TH];
    constexpr float st = ST8[TH];
    constexpr float sx = ct * (float)hxi - st * (float)hyi;
    constexpr float sy = st * (float)hxi + ct * (float)hyi;
    constexpr int dx = cfloor(sx);
    constexpr int dy = cfloor(sy);
    constexpr float wx = sx - (float)dx;
    constexpr float wy = sy - (float)dy;
    constexpr int R  = dy + 2;    // 0..3
    constexpr int Cb = dx + 2;    // 0..3

    const float k = sk[PP * 9 + OO];   // wave-uniform LDS broadcast
    #pragma unroll
    for (int j = 0; j < 4; ++j) {
        float v0, v1;
        if constexpr (wx == 0.0f && wy == 0.0f) {
            v0 = w[R][Cb + j];
            v1 = w[R + 1][Cb + j];
        } else if constexpr (wy == 0.0f) {
            const float a = w[R][Cb + j],     a1 = w[R][Cb + j + 1];
            const float b = w[R + 1][Cb + j], b1 = w[R + 1][Cb + j + 1];
            v0 = a + wx * (a1 - a);
            v1 = b + wx * (b1 - b);
        } else if constexpr (wx == 0.0f) {
            const float a  = w[R][Cb + j];
            const float b  = w[R + 1][Cb + j];
            const float cc = w[R + 2][Cb + j];
            v0 = a + wy * (b - a);
            v1 = b + wy * (cc - b);
        } else {
            const float a  = w[R][Cb + j],     a1  = w[R][Cb + j + 1];
            const float b  = w[R + 1][Cb + j], b1  = w[R + 1][Cb + j + 1];
            const float cc = w[R + 2][Cb + j], cc1 = w[R + 2][Cb + j + 1];
            const float h0 = a  + wx * (a1 - a);
            const float h1 = b  + wx * (b1 - b);      // shared by both rows
            const float h2 = cc + wx * (cc1 - cc);
            v0 = h0 + wy * (h1 - h0);
            v1 = h1 + wy * (h2 - h1);
        }
        ac0[j] = fmaxf(ac0[j], v0 - k);
        ac1[j] = fmaxf(ac1[j], v1 - k);
    }
}

template<int TH, int PP, int... OOs>
__device__ __forceinline__ void off_nine(std::integer_sequence<int, OOs...>,
        const float (&w)[6][8], const float* __restrict__ sk,
        float (&ac0)[4], float (&ac1)[4]) {
    (off_one<TH, PP, OOs>(w, sk, ac0, ac1), ...);
}

// Plane slot PP (hti = PP-1): 12 x 8B fp16 loads -> f32 6x8 window.
template<int TH, int PP>
__device__ __forceinline__ void do_plane(const _Float16* __restrict__ wb,
        const float* __restrict__ sk, float (&ac0)[4], float (&ac1)[4]) {
    constexpr int plane = (TH + PP - 1 + OR_) & 7;
    float w[6][8];
    const _Float16* __restrict__ base = wb + plane * PPL_;
    #pragma unroll
    for (int r = 0; r < 6; ++r) {
        const h4 lo = *(const h4*)&base[r * PW_];
        const h4 hi = *(const h4*)&base[r * PW_ + 4];
        #pragma unroll
        for (int j = 0; j < 4; ++j) {
            w[r][j]     = (float)lo[j];
            w[r][4 + j] = (float)hi[j];
        }
    }
    off_nine<TH, PP>(std::make_integer_sequence<int, 9>{}, w, sk, ac0, ac1);
}

template<int TH>
__device__ __forceinline__ void dil_theta(const _Float16* __restrict__ wb,
        const float* __restrict__ sk, float (&ac0)[4], float (&ac1)[4]) {
    do_plane<TH, 0>(wb, sk, ac0, ac1);
    do_plane<TH, 1>(wb, sk, ac0, ac1);
    do_plane<TH, 2>(wb, sk, ac0, ac1);
}

// block id = (n<<4)|c, n = th*18 + tile  ->  id%8 == c%8  (channel->XCD pin)
template<typename DstT>
__global__ __launch_bounds__(256) void dil_kernel(
        const _Float16* __restrict__ wsA, const float* __restrict__ mp,
        DstT* __restrict__ out) {
    __shared__ float s_k[27];

    const int id = blockIdx.x;
    const int c    = id & 15;
    const int n    = id >> 4;          // 0..143
    const int th   = n / 18;
    const int tile = n - th * 18;      // 0..17
    const int bx   = tile % 3;
    const int by   = tile / 3;         // 0..5
    const int t = threadIdx.x;

    if (t < 27) {
        const int hti = t / 9 - 1;
        const int hyi = (t / 3) % 3 - 1;
        const int hxi = t % 3 - 1;
        const float hx = (float)hxi, hy = (float)hyi;
        const float hth  = (float)hti * (2.0f * PI_F / OR_);
        const float half = 0.5f * hth;
        float q;
        if (fabsf(half) < 1e-4f) q = 1.0f - half * half * (1.0f / 3.0f);
        else                     q = half / tanf(half);
        const float c1 = q * hx + half * hy;
        const float c2 = -half * hx + q * hy;
        const float c3 = hth;
        const float m0 = mp[c * 3 + 0], m1 = mp[c * 3 + 1], m2 = mp[c * 3 + 2];
        const float d2 = (m0 * c1) * (m0 * c1) + (m1 * c2) * (m1 * c2) + (m2 * c3) * (m2 * c3);
        const float ee = 2.0f * 0.65f / (2.0f * 0.65f - 1.0f);
        const float nu = (2.0f * 0.65f - 1.0f) * powf(2.0f * 0.65f, -ee);
        s_k[t] = nu * powf(d2, 0.5f * ee);
    }
    __syncthreads();

    const int xg = t & 15;                       // 4 px: gx..gx+3
    const int ry = t >> 4;                       // 0..15, 2 rows each
    const int gx = bx * 64 + xg * 4;
    const int gy = by * 32 + ry * 2;

    // window base: padded (gy, gx) == image (gy-2, gx-2)
    const _Float16* __restrict__ wb = wsA + c * OR_ * PPL_ + gy * PW_ + gx;

    float ac0[4], ac1[4];
    #pragma unroll
    for (int j = 0; j < 4; ++j) { ac0[j] = -INFINITY; ac1[j] = -INFINITY; }

    switch (th) {
        case 0: dil_theta<0>(wb, s_k, ac0, ac1); break;
        case 1: dil_theta<1>(wb, s_k, ac0, ac1); break;
        case 2: dil_theta<2>(wb, s_k, ac0, ac1); break;
        case 3: dil_theta<3>(wb, s_k, ac0, ac1); break;
        case 4: dil_theta<4>(wb, s_k, ac0, ac1); break;
        case 5: dil_theta<5>(wb, s_k, ac0, ac1); break;
        case 6: dil_theta<6>(wb, s_k, ac0, ac1); break;
        case 7: dil_theta<7>(wb, s_k, ac0, ac1); break;
        default: __builtin_unreachable();
    }

    const int o = c * CH_ + th * HW_ + gy * W_ + gx;
    if constexpr (std::is_same_v<DstT, float>) {
        float4 r0, r1;
        r0.x = ac0[0]; r0.y = ac0[1]; r0.z = ac0[2]; r0.w = ac0[3];
        r1.x = ac1[0]; r1.y = ac1[1]; r1.z = ac1[2]; r1.w = ac1[3];
        *(float4*)&out[o] = r0;
        *(float4*)&out[o + W_] = r1;
    } else {
        h4 r0, r1;
        r0[0] = (_Float16)ac0[0]; r0[1] = (_Float16)ac0[1];
        r0[2] = (_Float16)ac0[2]; r0[3] = (_Float16)ac0[3];
        r1[0] = (_Float16)ac1[0]; r1[1] = (_Float16)ac1[1];
        r1[2] = (_Float16)ac1[2]; r1[3] = (_Float16)ac1[3];
        *(h4*)&out[o] = r0;
        *(h4*)&out[o + W_] = r1;
    }
}

} // anonymous namespace

extern "C" void kernel_launch(void* const* d_in, const int* in_sizes, int n_in,
                              void* d_out, int out_size, void* d_ws, size_t ws_size,
                              hipStream_t stream) {
    const float* u   = (const float*)d_in[0];
    const float* g0  = (const float*)d_in[1];
    const float* mpp = (const float*)d_in[2];
    float* out = (float*)d_out;
    _Float16* wsA = (_Float16*)d_ws;                 // padded fp16 conv output, 10.4 MB
    _Float16* wsB = wsA + NPL_ * PPL_;               // fp16 dil-1 output, 9.4 MB

    dim3 cgrid(288 * 16);                            // conv: 4608 blocks, 1-D XCD-pinned
    dim3 dgrid(144 * 16);                            // dil:  2304 blocks, 1-D XCD-pinned
    dim3 block(256);

    // iter 1
    conv_kernel<float>   <<<cgrid, block, 0, stream>>>(u,   g0,  wsA);
    dil_kernel<_Float16> <<<dgrid, block, 0, stream>>>(wsA, mpp, wsB);
    // iter 2
    conv_kernel<_Float16><<<cgrid, block, 0, stream>>>(wsB, g0,  wsA);
    dil_kernel<float>    <<<dgrid, block, 0, stream>>>(wsA, mpp, out);
}